// Round 1
// 1369.554 us; speedup vs baseline: 1.1820x; 1.1820x over previous
//
#include <hip/hip_runtime.h>

// DCCF encoder: U=100000, I=50000, D=64, K=128, L=2, E=1250000, N=150000. f32.
//
// d_out layout (float): [final NxD][gnn LxNxD][intl LxNxD][gaa LxNxD][iaa LxNxD]
//
// R3 changes vs R2:
//  - intent_kernel rewritten: lane = node (64 nodes/wave, 1 wave/block).
//    Softmax is fully lane-local (zero cross-lane ops). W operand is
//    wave-uniform -> scalar s_load + v_fmac (1 FMA/instr, was 2 FMA per
//    4 instr + 4-way-conflicted ds_read_b64). e staged via padded-65 LDS
//    transpose (2-way bank aliasing = free). P round-trips through the same
//    LDS tile in two 64-row halves so rolled k-loops never runtime-index a
//    register array (rule: dyn-indexed reg arrays -> scratch).
//  - W^T precomputed once into workspace (phase-2 scalar loads need
//    contiguous rows of W^T).
//  - __launch_bounds__(64): without it the default 1024-thread bound caps
//    VGPRs at 128 and spills a[128].

#define U_CNT 100000
#define I_CNT 50000
#define D_DIM 64
#define K_DIM 128
#define L_LAYERS 2
#define E_CNT 1250000
#define N_CNT (U_CNT + I_CNT)
#define EPSF 1e-12f

#define UBLK ((U_CNT + 63) / 64)  // 1563 (last block: 32 users)
#define IBLK ((I_CNT + 63) / 64)  // 782  (last block: 16 items)

__device__ __forceinline__ float wave_sum(float v) {
#pragma unroll
  for (int off = 32; off > 0; off >>= 1) v += __shfl_xor(v, off, 64);
  return v;
}

__global__ void init_kernel(const float* __restrict__ ue, const float* __restrict__ ie,
                            float* __restrict__ ek, float* __restrict__ fin) {
  int idx = blockIdx.x * blockDim.x + threadIdx.x;
  const int total = N_CNT * D_DIM;
  for (; idx < total; idx += gridDim.x * blockDim.x) {
    float v = (idx < U_CNT * D_DIM) ? ue[idx] : ie[idx - U_CNT * D_DIM];
    ek[idx] = v;
    fin[idx] = v;
  }
}

__global__ void hist_kernel(const int* __restrict__ h_idx, int* __restrict__ counts) {
  int e = blockIdx.x * blockDim.x + threadIdx.x;
  for (; e < E_CNT; e += gridDim.x * blockDim.x) atomicAdd(&counts[h_idx[e]], 1);
}

__global__ void scan_kernel(const int* __restrict__ counts, int* __restrict__ row_ptr,
                            int* __restrict__ cursor) {
  __shared__ int wsum[16];
  __shared__ int s_carry, s_total;
  int tid = threadIdx.x, lane = tid & 63, wv = tid >> 6;
  if (tid == 0) s_carry = 0;
  __syncthreads();
  for (int base = 0; base < N_CNT; base += 4096) {
    int idx = base + tid * 4;
    int v0 = (idx + 0 < N_CNT) ? counts[idx + 0] : 0;
    int v1 = (idx + 1 < N_CNT) ? counts[idx + 1] : 0;
    int v2 = (idx + 2 < N_CNT) ? counts[idx + 2] : 0;
    int v3 = (idx + 3 < N_CNT) ? counts[idx + 3] : 0;
    int s = v0 + v1 + v2 + v3;
    int x = s;
#pragma unroll
    for (int off = 1; off < 64; off <<= 1) {
      int y = __shfl_up(x, off, 64);
      if (lane >= off) x += y;
    }
    if (lane == 63) wsum[wv] = x;
    __syncthreads();
    if (wv == 0 && lane < 16) {
      int w = wsum[lane];
      int xx = w;
#pragma unroll
      for (int off = 1; off < 16; off <<= 1) {
        int y = __shfl_up(xx, off, 64);
        if (lane >= off) xx += y;
      }
      wsum[lane] = xx - w;
      if (lane == 15) s_total = xx;
    }
    __syncthreads();
    int carry = s_carry;
    int e0 = carry + wsum[wv] + (x - s);
    int e1 = e0 + v0, e2 = e1 + v1, e3 = e2 + v2;
    if (idx + 0 < N_CNT) { row_ptr[idx + 0] = e0; cursor[idx + 0] = e0; }
    if (idx + 1 < N_CNT) { row_ptr[idx + 1] = e1; cursor[idx + 1] = e1; }
    if (idx + 2 < N_CNT) { row_ptr[idx + 2] = e2; cursor[idx + 2] = e2; }
    if (idx + 3 < N_CNT) { row_ptr[idx + 3] = e3; cursor[idx + 3] = e3; }
    __syncthreads();
    if (tid == 0) s_carry = carry + s_total;
    __syncthreads();
  }
  if (threadIdx.x == 0) row_ptr[N_CNT] = s_carry;
}

__global__ void scatter_kernel(const int* __restrict__ h_idx, const int* __restrict__ t_idx,
                               const float* __restrict__ adj_vals, int* __restrict__ cursor,
                               int* __restrict__ t_sorted, float* __restrict__ v_sorted) {
  int e = blockIdx.x * blockDim.x + threadIdx.x;
  for (; e < E_CNT; e += gridDim.x * blockDim.x) {
    int h = h_idx[e];
    int pos = atomicAdd(&cursor[h], 1);
    t_sorted[pos] = t_idx[e];
    v_sorted[pos] = adj_vals[e];
  }
}

// One-shot: W [64][128] -> WT [128][64] for both intent matrices.
__global__ void transposeW_kernel(const float* __restrict__ Wu, const float* __restrict__ Wi,
                                  float* __restrict__ WuT, float* __restrict__ WiT) {
  int idx = blockIdx.x * blockDim.x + threadIdx.x;
  for (; idx < 2 * D_DIM * K_DIM; idx += gridDim.x * blockDim.x) {
    int w = idx >> 13, r = idx & (D_DIM * K_DIM - 1);
    int d = r >> 7, k = r & (K_DIM - 1);
    const float* W = w ? Wi : Wu;
    float* WT = w ? WiT : WuT;
    WT[k * D_DIM + d] = W[d * K_DIM + k];
  }
}

// gnn = spmm(adj_vals, ek), 4 edges/iter, float4 lanes; also 1/||gnn row||
__global__ void spmm_gnn_kernel(const float* __restrict__ ek, const int* __restrict__ t_sorted,
                                const float* __restrict__ v_sorted,
                                const int* __restrict__ row_ptr, float* __restrict__ gnn,
                                float* __restrict__ invn_g) {
  int wv = threadIdx.x >> 6, lane = threadIdx.x & 63;
  int slot = lane >> 4, f = (lane & 15) << 2;
  int n = blockIdx.x * 4 + wv;
  if (n >= N_CNT) return;
  int start = row_ptr[n], end = row_ptr[n + 1];
  float ax = 0.f, ay = 0.f, az = 0.f, aw = 0.f;
  for (int i = start; i < end; i += 4) {
    int idx = i + slot;
    int ic = (idx < end) ? idx : (end - 1);
    int t = t_sorted[ic];
    float v = v_sorted[ic];
    if (idx >= end) v = 0.f;
    const float4 x = *(const float4*)(ek + (size_t)t * D_DIM + f);
    ax = fmaf(v, x.x, ax);
    ay = fmaf(v, x.y, ay);
    az = fmaf(v, x.z, az);
    aw = fmaf(v, x.w, aw);
  }
#pragma unroll
  for (int off = 16; off <= 32; off <<= 1) {
    ax += __shfl_xor(ax, off, 64);
    ay += __shfl_xor(ay, off, 64);
    az += __shfl_xor(az, off, 64);
    aw += __shfl_xor(aw, off, 64);
  }
  if (slot == 0) {
    float4 o = make_float4(ax, ay, az, aw);
    *(float4*)(gnn + (size_t)n * D_DIM + f) = o;
  }
  float ss = ax * ax + ay * ay + az * az + aw * aw;
#pragma unroll
  for (int off = 1; off <= 8; off <<= 1) ss += __shfl_xor(ss, off, 64);
  if (lane == 0) invn_g[n] = 1.f / fmaxf(sqrtf(ss), EPSF);
}

// intl = softmax(ek @ W) @ W^T. lane = node, 64 nodes per wave, 1 wave/block.
// a[k] and o[d] lane-local; softmax lane-local; W via wave-uniform scalar loads.
__global__ __launch_bounds__(64) void intent_kernel(
    const float* __restrict__ ek, const float* __restrict__ Wu, const float* __restrict__ WuT,
    const float* __restrict__ Wi, const float* __restrict__ WiT, float* __restrict__ intl,
    float* __restrict__ invn_i) {
  __shared__ float T[D_DIM * 65];  // padded: bank = (word + row-ish) -> 2-way max
  const int lane = threadIdx.x;
  const int b = blockIdx.x;
  int n0, cnt;
  const float *W, *WT;
  if (b < UBLK) {
    n0 = b * 64;
    cnt = (U_CNT - n0 < 64) ? (U_CNT - n0) : 64;
    W = Wu;
    WT = WuT;
  } else {
    n0 = U_CNT + (b - UBLK) * 64;
    cnt = (N_CNT - n0 < 64) ? (N_CNT - n0) : 64;
    W = Wi;
    WT = WiT;
  }
  const int h = lane >> 4, m = lane & 15;

  // Phase 0: coalesced float4 loads of 64 node rows -> transposed into LDS.
  // T[d*65 + node]. Write banks: (4m + j + 4i + h) % 32 -> 2 lanes/bank (free).
#pragma unroll
  for (int i = 0; i < 16; i++) {
    int r = i * 4 + h;  // node row within tile
    float4 v = make_float4(0.f, 0.f, 0.f, 0.f);
    if (r < cnt) v = *(const float4*)(ek + (size_t)(n0 + r) * D_DIM + m * 4);
    T[(4 * m + 0) * 65 + r] = v.x;
    T[(4 * m + 1) * 65 + r] = v.y;
    T[(4 * m + 2) * 65 + r] = v.z;
    T[(4 * m + 3) * 65 + r] = v.w;
  }
  __syncthreads();

  // Phase 1: a[k] = sum_d e[d] * W[d][k]. W row is wave-uniform -> s_load.
  float a[K_DIM];
#pragma unroll
  for (int k = 0; k < K_DIM; k++) a[k] = 0.f;
#pragma unroll 2
  for (int d = 0; d < D_DIM; d++) {
    float ed = T[d * 65 + lane];  // bank (d+lane)%32 -> 2-way, free
    const float* __restrict__ wr = W + d * K_DIM;
#pragma unroll
    for (int k = 0; k < K_DIM; k++) a[k] = fmaf(wr[k], ed, a[k]);
  }

  // Lane-local softmax over a[0..127] (4 chains to break dep latency).
  float m0 = a[0], m1 = a[1], m2 = a[2], m3 = a[3];
#pragma unroll
  for (int k = 4; k < K_DIM; k += 4) {
    m0 = fmaxf(m0, a[k]);
    m1 = fmaxf(m1, a[k + 1]);
    m2 = fmaxf(m2, a[k + 2]);
    m3 = fmaxf(m3, a[k + 3]);
  }
  float mx = fmaxf(fmaxf(m0, m1), fmaxf(m2, m3));
  float s0 = 0.f, s1 = 0.f, s2 = 0.f, s3 = 0.f;
#pragma unroll
  for (int k = 0; k < K_DIM; k += 4) {
    a[k] = __expf(a[k] - mx);
    s0 += a[k];
    a[k + 1] = __expf(a[k + 1] - mx);
    s1 += a[k + 1];
    a[k + 2] = __expf(a[k + 2] - mx);
    s2 += a[k + 2];
    a[k + 3] = __expf(a[k + 3] - mx);
    s3 += a[k + 3];
  }
  float inv_s = 1.f / ((s0 + s1) + (s2 + s3));  // normalize folded into epilogue

  // Phase 2: o[d] = sum_k p[k] * WT[k][d], k rolled. p streamed via LDS in two
  // 64-row halves so the rolled k never runtime-indexes a register array.
  float o[D_DIM];
#pragma unroll
  for (int d = 0; d < D_DIM; d++) o[d] = 0.f;

  __syncthreads();
#pragma unroll
  for (int k = 0; k < 64; k++) T[k * 65 + lane] = a[k];
  __syncthreads();
#pragma unroll 2
  for (int k = 0; k < 64; k++) {
    float pk = T[k * 65 + lane];
    const float* __restrict__ wr = WT + k * D_DIM;
#pragma unroll
    for (int d = 0; d < D_DIM; d++) o[d] = fmaf(wr[d], pk, o[d]);
  }
  __syncthreads();
#pragma unroll
  for (int k = 0; k < 64; k++) T[k * 65 + lane] = a[k + 64];
  __syncthreads();
#pragma unroll 2
  for (int k = 0; k < 64; k++) {
    float pk = T[k * 65 + lane];
    const float* __restrict__ wr = WT + (k + 64) * D_DIM;
#pragma unroll
    for (int d = 0; d < D_DIM; d++) o[d] = fmaf(wr[d], pk, o[d]);
  }

  // Epilogue: normalize, row inv-norm, transpose back through LDS, coalesced store.
  float ns = 0.f;
#pragma unroll
  for (int d = 0; d < D_DIM; d++) {
    o[d] *= inv_s;
    ns = fmaf(o[d], o[d], ns);
  }
  if (lane < cnt) invn_i[n0 + lane] = 1.f / fmaxf(sqrtf(ns), EPSF);

  __syncthreads();
#pragma unroll
  for (int d = 0; d < D_DIM; d++) T[d * 65 + lane] = o[d];
  __syncthreads();
#pragma unroll
  for (int i = 0; i < 16; i++) {
    int r = i * 4 + h;
    if (r < cnt) {
      float4 v = make_float4(T[(4 * m + 0) * 65 + r], T[(4 * m + 1) * 65 + r],
                             T[(4 * m + 2) * 65 + r], T[(4 * m + 3) * 65 + r]);
      *(float4*)(intl + (size_t)(n0 + r) * D_DIM + m * 4) = v;
    }
  }
}

// Fused adaptive pass: 4 edges/iter, float4 lanes. Computes both alphas, row
// sums, alpha-weighted ek accum (d_inv factored out), gaa/iaa, next ek, final.
__global__ void passB_kernel(const float* __restrict__ ek, const float* __restrict__ gnn,
                             const float* __restrict__ intl, const float* __restrict__ invn_g,
                             const float* __restrict__ invn_i, const int* __restrict__ t_sorted,
                             const int* __restrict__ row_ptr, float* __restrict__ gaa,
                             float* __restrict__ iaa, float* __restrict__ ek_next,
                             float* __restrict__ fin) {
  int wv = threadIdx.x >> 6, lane = threadIdx.x & 63;
  int slot = lane >> 4, f = (lane & 15) << 2;
  int n = blockIdx.x * 4 + wv;
  if (n >= N_CNT) return;
  int start = row_ptr[n], end = row_ptr[n + 1];
  const float4 gh = *(const float4*)(gnn + (size_t)n * D_DIM + f);
  const float4 ih = *(const float4*)(intl + (size_t)n * D_DIM + f);
  float ig = invn_g[n], ii = invn_i[n];
  float rs_g = 0.f, rs_i = 0.f;
  float gx = 0.f, gy = 0.f, gz = 0.f, gw = 0.f;
  float ix = 0.f, iy = 0.f, iz = 0.f, iw = 0.f;
  for (int i = start; i < end; i += 4) {
    int idx = i + slot;
    int ic = (idx < end) ? idx : (end - 1);
    int t = t_sorted[ic];
    size_t rb = (size_t)t * D_DIM + f;
    const float4 gt = *(const float4*)(gnn + rb);
    const float4 it = *(const float4*)(intl + rb);
    const float4 et = *(const float4*)(ek + rb);
    float ivg = invn_g[t];
    float ivi = invn_i[t];
    float dg = gh.x * gt.x + gh.y * gt.y + gh.z * gt.z + gh.w * gt.w;
    float di = ih.x * it.x + ih.y * it.y + ih.z * it.z + ih.w * it.w;
#pragma unroll
    for (int off = 1; off <= 8; off <<= 1) {
      dg += __shfl_xor(dg, off, 64);
      di += __shfl_xor(di, off, 64);
    }
    float ag = fmaf(dg * ig, ivg, 1.f) * 0.5f;
    float ai = fmaf(di * ii, ivi, 1.f) * 0.5f;
    if (idx >= end) { ag = 0.f; ai = 0.f; }
    rs_g += ag;
    rs_i += ai;
    gx = fmaf(ag, et.x, gx);
    gy = fmaf(ag, et.y, gy);
    gz = fmaf(ag, et.z, gz);
    gw = fmaf(ag, et.w, gw);
    ix = fmaf(ai, et.x, ix);
    iy = fmaf(ai, et.y, iy);
    iz = fmaf(ai, et.z, iz);
    iw = fmaf(ai, et.w, iw);
  }
#pragma unroll
  for (int off = 16; off <= 32; off <<= 1) {
    rs_g += __shfl_xor(rs_g, off, 64);
    rs_i += __shfl_xor(rs_i, off, 64);
    gx += __shfl_xor(gx, off, 64);
    gy += __shfl_xor(gy, off, 64);
    gz += __shfl_xor(gz, off, 64);
    gw += __shfl_xor(gw, off, 64);
    ix += __shfl_xor(ix, off, 64);
    iy += __shfl_xor(iy, off, 64);
    iz += __shfl_xor(iz, off, 64);
    iw += __shfl_xor(iw, off, 64);
  }
  float dgi = (rs_g > 0.f) ? 1.f / rs_g : 0.f;
  float dii = (rs_i > 0.f) ? 1.f / rs_i : 0.f;
  if (slot == 0) {
    size_t ob = (size_t)n * D_DIM + f;
    float4 ga = make_float4(gx * dgi, gy * dgi, gz * dgi, gw * dgi);
    float4 ia = make_float4(ix * dii, iy * dii, iz * dii, iw * dii);
    *(float4*)(gaa + ob) = ga;
    *(float4*)(iaa + ob) = ia;
    const float4 eh = *(const float4*)(ek + ob);
    float4 en = make_float4(gh.x + ih.x + ga.x + ia.x + eh.x, gh.y + ih.y + ga.y + ia.y + eh.y,
                            gh.z + ih.z + ga.z + ia.z + eh.z, gh.w + ih.w + ga.w + ia.w + eh.w);
    *(float4*)(ek_next + ob) = en;
    float4 fo = *(const float4*)(fin + ob);
    fo.x += en.x;
    fo.y += en.y;
    fo.z += en.z;
    fo.w += en.w;
    *(float4*)(fin + ob) = fo;
  }
}

extern "C" void kernel_launch(void* const* d_in, const int* in_sizes, int n_in, void* d_out,
                              int out_size, void* d_ws, size_t ws_size, hipStream_t stream) {
  const float* user_emb = (const float*)d_in[0];
  const float* item_emb = (const float*)d_in[1];
  const float* user_intent = (const float*)d_in[2];
  const float* item_intent = (const float*)d_in[3];
  const float* adj_vals = (const float*)d_in[4];
  const int* h_idx = (const int*)d_in[5];
  const int* t_idx = (const int*)d_in[6];

  float* out = (float*)d_out;
  float* fin = out;
  float* gnn_base = out + (size_t)N_CNT * D_DIM;
  float* intl_base = gnn_base + (size_t)L_LAYERS * N_CNT * D_DIM;
  float* gaa_base = intl_base + (size_t)L_LAYERS * N_CNT * D_DIM;
  float* iaa_base = gaa_base + (size_t)L_LAYERS * N_CNT * D_DIM;

  float* ws = (float*)d_ws;
  float* ekA = ws;                                // N*D
  float* ekB = ekA + (size_t)N_CNT * D_DIM;       // N*D
  float* v_sorted = ekB + (size_t)N_CNT * D_DIM;  // E
  float* invn_g = v_sorted + E_CNT;               // N
  float* invn_i = invn_g + N_CNT;                 // N
  int* t_sorted = (int*)(invn_i + N_CNT);         // E
  int* row_ptr = t_sorted + E_CNT;                // N+1
  int* counts = row_ptr + (N_CNT + 1);            // N
  int* cursor = counts + N_CNT;                   // N
  float* wtu = (float*)(cursor + N_CNT);          // D*K  (W_u^T)
  float* wti = wtu + (size_t)D_DIM * K_DIM;       // D*K  (W_i^T)

  hipMemsetAsync(counts, 0, N_CNT * sizeof(int), stream);
  init_kernel<<<2048, 256, 0, stream>>>(user_emb, item_emb, ekA, fin);
  hist_kernel<<<2048, 256, 0, stream>>>(h_idx, counts);
  transposeW_kernel<<<32, 512, 0, stream>>>(user_intent, item_intent, wtu, wti);
  scan_kernel<<<1, 1024, 0, stream>>>(counts, row_ptr, cursor);
  scatter_kernel<<<2048, 256, 0, stream>>>(h_idx, t_idx, adj_vals, cursor, t_sorted, v_sorted);

  float* ek = ekA;
  float* ekn = ekB;
  const int nodeBlocks = (N_CNT + 3) / 4;
  const int intentBlocks = UBLK + IBLK;
  for (int l = 0; l < L_LAYERS; l++) {
    float* gnn = gnn_base + (size_t)l * N_CNT * D_DIM;
    float* intl = intl_base + (size_t)l * N_CNT * D_DIM;
    float* gaa = gaa_base + (size_t)l * N_CNT * D_DIM;
    float* iaa = iaa_base + (size_t)l * N_CNT * D_DIM;
    spmm_gnn_kernel<<<nodeBlocks, 256, 0, stream>>>(ek, t_sorted, v_sorted, row_ptr, gnn, invn_g);
    intent_kernel<<<intentBlocks, 64, 0, stream>>>(ek, user_intent, wtu, item_intent, wti, intl,
                                                   invn_i);
    passB_kernel<<<nodeBlocks, 256, 0, stream>>>(ek, gnn, intl, invn_g, invn_i, t_sorted, row_ptr,
                                                 gaa, iaa, ekn, fin);
    float* tmp = ek;
    ek = ekn;
    ekn = tmp;
  }
}